// Round 1
// baseline (667.814 us; speedup 1.0000x reference)
//
#include <hip/hip_runtime.h>
#include <hip/hip_bf16.h>
#include <cstddef>
#include <cstdint>

// Problem constants
static constexpr int BSZ  = 8;
static constexpr int NN   = 512;   // nodes
static constexpr int FF   = 512;   // features
static constexpr int RR   = 16;    // relations
static constexpr int TWOF = 1024;

// ---------------------------------------------------------------------------
// Workspace layout (in floats)
// ---------------------------------------------------------------------------
static constexpr size_t OFF_T    = 0;                       // [8][512]
static constexpr size_t OFF_M    = OFF_T    + BSZ * FF;     // [8][512]
static constexpr size_t OFF_MQ   = OFF_M    + BSZ * FF;     // [8][512]
static constexpr size_t OFF_MK   = OFF_MQ   + BSZ * FF;     // [8][512]
static constexpr size_t OFF_WQE  = OFF_MK   + BSZ * FF;     // [8][1024][16]
static constexpr size_t OFF_WKE  = OFF_WQE  + BSZ * TWOF * RR;
static constexpr size_t OFF_SQ   = OFF_WKE  + BSZ * TWOF * RR;  // [8][512][16]
static constexpr size_t OFF_SK   = OFF_SQ   + BSZ * NN * RR;
static constexpr size_t OFF_ATTN = OFF_SK   + BSZ * NN * RR;    // [8][512][512]
static constexpr size_t OFF_NEWX = OFF_ATTN + (size_t)BSZ * NN * NN; // [8][512][512]

// ---------------------------------------------------------------------------
// 1) Batched matvec: vout[b,f] = (optional elu)( vin[b,:] @ W[:, f] )
//    grid (2, 8), block 256 — thread per output f
// ---------------------------------------------------------------------------
__global__ __launch_bounds__(256) void k_matvec(const float* __restrict__ vin,
                                                const float* __restrict__ W,
                                                float* __restrict__ vout,
                                                int elu_out) {
    int t = threadIdx.x;
    int b = blockIdx.y;
    int f = blockIdx.x * 256 + t;
    const float* vb = vin + (size_t)b * FF;
    float acc = 0.f;
#pragma unroll 4
    for (int k = 0; k < FF; ++k) {
        acc = fmaf(vb[k], W[(size_t)k * FF + f], acc);
    }
    if (elu_out) acc = (acc > 0.f) ? acc : expm1f(acc);
    vout[(size_t)b * FF + f] = acc;
}

// ---------------------------------------------------------------------------
// 2) mq = m @ Wqc ; mk = m @ Wkc    grid (2, 8), block 256
// ---------------------------------------------------------------------------
__global__ __launch_bounds__(256) void k_mqk(const float* __restrict__ m,
                                             const float* __restrict__ Wqc,
                                             const float* __restrict__ Wkc,
                                             float* __restrict__ mq,
                                             float* __restrict__ mk) {
    int t = threadIdx.x;
    int b = blockIdx.y;
    int f = blockIdx.x * 256 + t;
    const float* mb = m + (size_t)b * FF;
    float aq = 0.f, ak = 0.f;
#pragma unroll 4
    for (int k = 0; k < FF; ++k) {
        float mv = mb[k];
        aq = fmaf(mv, Wqc[(size_t)k * FF + f], aq);
        ak = fmaf(mv, Wkc[(size_t)k * FF + f], ak);
    }
    mq[(size_t)b * FF + f] = aq;
    mk[(size_t)b * FF + f] = ak;
}

// ---------------------------------------------------------------------------
// 3) W_eff[b,k,r] = sum_f W[k,f] * mvec[b,f] * Wa[waRowOff + f, r]
//    grid (16 kchunks, 8 b), block 256.  LDS holds mvec-scaled Wa [512][16].
// ---------------------------------------------------------------------------
__global__ __launch_bounds__(256) void k_weff(const float* __restrict__ W,
                                              const float* __restrict__ Wa,
                                              const float* __restrict__ mvec,
                                              float* __restrict__ Weff,
                                              int waRowOff) {
    __shared__ float4 wa4[FF * 4];  // [f][r4] as float4 -> 32 KiB
    int tid = threadIdx.x;
    int b = blockIdx.y;
    const float* mv = mvec + (size_t)b * FF;
#pragma unroll
    for (int q = 0; q < 8; ++q) {
        int idx = tid + q * 256;         // 0..2047
        int f = idx >> 2, rq = idx & 3;
        float4 w = *reinterpret_cast<const float4*>(Wa + (size_t)(waRowOff + f) * RR + rq * 4);
        float s = mv[f];
        float4 o;
        o.x = w.x * s; o.y = w.y * s; o.z = w.z * s; o.w = w.w * s;
        wa4[idx] = o;
    }
    __syncthreads();
    int k_l = tid >> 2, r4 = tid & 3;
    int k = blockIdx.x * 64 + k_l;
    const float* Wrow = W + (size_t)k * FF;
    float4 acc = {0.f, 0.f, 0.f, 0.f};
#pragma unroll 4
    for (int f = 0; f < FF; ++f) {
        float w = Wrow[f];
        float4 v = wa4[f * 4 + r4];
        acc.x = fmaf(w, v.x, acc.x);
        acc.y = fmaf(w, v.y, acc.y);
        acc.z = fmaf(w, v.z, acc.z);
        acc.w = fmaf(w, v.w, acc.w);
    }
    reinterpret_cast<float4*>(Weff)[((size_t)b * TWOF + k) * 4 + r4] = acc;
}

// ---------------------------------------------------------------------------
// 4) sq[b,i,r] = nodes[b,i,:] @ WqE[b,:,r] ; sk likewise.
//    nodes[b,i,k] = k<512 ? x[b,i,k] : x_ori[b,i,k-512]
//    grid (32 ichunks, 8 b), block 256 = (16 r, 16 i)
// ---------------------------------------------------------------------------
__global__ __launch_bounds__(256) void k_sqsk(const float* __restrict__ x,
                                              const float* __restrict__ x_ori,
                                              const float* __restrict__ WqE,
                                              const float* __restrict__ WkE,
                                              float* __restrict__ sq,
                                              float* __restrict__ sk) {
    __shared__ float nl[16 * 516];  // 16 rows, stride 516 (pad, 16B-aligned) ~33 KiB
    int tid = threadIdx.x;
    int b = blockIdx.y;
    int i0 = blockIdx.x * 16;
    int r = tid & 15, i_l = tid >> 4;
    float accq = 0.f, acck = 0.f;
    for (int half = 0; half < 2; ++half) {
        const float* src = half ? x_ori : x;
#pragma unroll
        for (int q = 0; q < 8; ++q) {
            int idx = tid + q * 256;       // 0..2047 float4s
            int i_ld = idx >> 7, k4 = idx & 127;
            float4 v = *reinterpret_cast<const float4*>(
                src + ((size_t)(b * NN + i0 + i_ld) * FF + k4 * 4));
            *reinterpret_cast<float4*>(&nl[i_ld * 516 + k4 * 4]) = v;
        }
        __syncthreads();
        const float* wq = WqE + ((size_t)b * TWOF + half * FF) * RR + r;
        const float* wk = WkE + ((size_t)b * TWOF + half * FF) * RR + r;
        const float* row = &nl[i_l * 516];
#pragma unroll 4
        for (int k = 0; k < FF; ++k) {
            float v = row[k];
            accq = fmaf(v, wq[k * RR], accq);
            acck = fmaf(v, wk[k * RR], acck);
        }
        __syncthreads();
    }
    int i = i0 + i_l;
    sq[((size_t)b * NN + i) * RR + r] = accq;
    sk[((size_t)b * NN + i) * RR + r] = acck;
}

// ---------------------------------------------------------------------------
// 5) Fused scores + mask + softmax -> attn.  grid (512 i, 8 b), block 256.
//    s[b,i,j] = sum_r adj[b,i,j,r] * leakyrelu(sq[b,i,r] + sk[b,j,r], 0.2)
// ---------------------------------------------------------------------------
__global__ __launch_bounds__(256) void k_attn(const int* __restrict__ adj,
                                              const float* __restrict__ sq,
                                              const float* __restrict__ sk,
                                              float* __restrict__ attn) {
    int t = threadIdx.x;
    int i = blockIdx.x;
    int b = blockIdx.y;
    __shared__ float sqv_s[RR];
    __shared__ float redmax[4];
    __shared__ float redsum[4];
    __shared__ float bc_max;
    __shared__ float bc_sum;
    if (t < RR) sqv_s[t] = sq[((size_t)b * NN + i) * RR + t];
    __syncthreads();
    float sv[RR];
#pragma unroll
    for (int r = 0; r < RR; ++r) sv[r] = sqv_s[r];

    float z[2];
#pragma unroll
    for (int jj = 0; jj < 2; ++jj) {
        int j = t + jj * 256;
        size_t base = ((size_t)(b * NN + i) * NN + j) * RR;
        const int4* ap = reinterpret_cast<const int4*>(adj + base);
        int4 a0 = ap[0], a1 = ap[1], a2 = ap[2], a3 = ap[3];
        const float4* kp = reinterpret_cast<const float4*>(sk + ((size_t)b * NN + j) * RR);
        float4 s0 = kp[0], s1 = kp[1], s2 = kp[2], s3 = kp[3];
        int sum_adj = a0.x + a0.y + a0.z + a0.w + a1.x + a1.y + a1.z + a1.w +
                      a2.x + a2.y + a2.z + a2.w + a3.x + a3.y + a3.z + a3.w;
        float ssum = 0.f;
#define LR_TERM(SVAL, AVAL, RIDX)                                   \
        { float v_ = sv[RIDX] + (SVAL);                             \
          v_ = (v_ > 0.f) ? v_ : 0.2f * v_;                         \
          ssum = fmaf(v_, (float)(AVAL), ssum); }
        LR_TERM(s0.x, a0.x, 0)  LR_TERM(s0.y, a0.y, 1)
        LR_TERM(s0.z, a0.z, 2)  LR_TERM(s0.w, a0.w, 3)
        LR_TERM(s1.x, a1.x, 4)  LR_TERM(s1.y, a1.y, 5)
        LR_TERM(s1.z, a1.z, 6)  LR_TERM(s1.w, a1.w, 7)
        LR_TERM(s2.x, a2.x, 8)  LR_TERM(s2.y, a2.y, 9)
        LR_TERM(s2.z, a2.z, 10) LR_TERM(s2.w, a2.w, 11)
        LR_TERM(s3.x, a3.x, 12) LR_TERM(s3.y, a3.y, 13)
        LR_TERM(s3.z, a3.z, 14) LR_TERM(s3.w, a3.w, 15)
#undef LR_TERM
        z[jj] = (sum_adj > 0) ? ssum : -9e15f;
    }

    int wv = t >> 6, ln = t & 63;
    // block max
    float lm = fmaxf(z[0], z[1]);
    for (int off = 32; off; off >>= 1) lm = fmaxf(lm, __shfl_xor(lm, off, 64));
    if (ln == 0) redmax[wv] = lm;
    __syncthreads();
    if (t == 0) bc_max = fmaxf(fmaxf(redmax[0], redmax[1]), fmaxf(redmax[2], redmax[3]));
    __syncthreads();
    float mx = bc_max;
    float e0 = __expf(z[0] - mx);
    float e1 = __expf(z[1] - mx);
    // block sum
    float ls = e0 + e1;
    for (int off = 32; off; off >>= 1) ls += __shfl_xor(ls, off, 64);
    if (ln == 0) redsum[wv] = ls;
    __syncthreads();
    if (t == 0) bc_sum = redsum[0] + redsum[1] + redsum[2] + redsum[3];
    __syncthreads();
    float inv = 1.f / bc_sum;
    float* out = attn + (size_t)(b * NN + i) * NN;
    out[t] = e0 * inv;
    out[t + 256] = e1 * inv;
}

// ---------------------------------------------------------------------------
// 6) Tiled fp32 GEMM, 64x64 C-tile, 4x4 microtile, BK=16.
//    C[b] = [A1 | A2][b] (M x K) @ B[b] (K x 512),  lda = ldb = ldc = 512.
//    A row k<512 from A1, k>=512 from A2.  grid (8 n, 8 m, 8 b), block 256.
// ---------------------------------------------------------------------------
__global__ __launch_bounds__(256) void k_gemm64(const float* __restrict__ A1, size_t sA1,
                                                const float* __restrict__ A2, size_t sA2,
                                                const float* __restrict__ B, size_t sB,
                                                float* __restrict__ C, size_t sC,
                                                int K) {
    __shared__ float As[16 * 68];
    __shared__ float Bs[16 * 68];
    int tid = threadIdx.x;
    int tx = tid & 15, ty = tid >> 4;
    int n0 = blockIdx.x * 64, m0 = blockIdx.y * 64, b = blockIdx.z;
    float acc[4][4] = {};
    const float* Bb = B + (size_t)b * sB;
    for (int k0 = 0; k0 < K; k0 += 16) {
        const float* Ab;
        int kl;
        if (k0 < FF) { Ab = A1 + (size_t)b * sA1; kl = k0; }
        else         { Ab = A2 + (size_t)b * sA2; kl = k0 - FF; }
#pragma unroll
        for (int q = 0; q < 4; ++q) {
            int idx = tid + q * 256;            // 1024 = 64m x 16k
            int kk = idx & 15, mm = idx >> 4;
            As[kk * 68 + mm] = Ab[(size_t)(m0 + mm) * FF + kl + kk];
        }
#pragma unroll
        for (int q = 0; q < 4; ++q) {
            int idx = tid + q * 256;            // 1024 = 16k x 64n
            int nn = idx & 63, kk = idx >> 6;
            Bs[kk * 68 + nn] = Bb[(size_t)(k0 + kk) * FF + n0 + nn];
        }
        __syncthreads();
#pragma unroll
        for (int kk = 0; kk < 16; ++kk) {
            float4 a  = *reinterpret_cast<const float4*>(&As[kk * 68 + ty * 4]);
            float4 bb = *reinterpret_cast<const float4*>(&Bs[kk * 68 + tx * 4]);
            acc[0][0] = fmaf(a.x, bb.x, acc[0][0]);
            acc[0][1] = fmaf(a.x, bb.y, acc[0][1]);
            acc[0][2] = fmaf(a.x, bb.z, acc[0][2]);
            acc[0][3] = fmaf(a.x, bb.w, acc[0][3]);
            acc[1][0] = fmaf(a.y, bb.x, acc[1][0]);
            acc[1][1] = fmaf(a.y, bb.y, acc[1][1]);
            acc[1][2] = fmaf(a.y, bb.z, acc[1][2]);
            acc[1][3] = fmaf(a.y, bb.w, acc[1][3]);
            acc[2][0] = fmaf(a.z, bb.x, acc[2][0]);
            acc[2][1] = fmaf(a.z, bb.y, acc[2][1]);
            acc[2][2] = fmaf(a.z, bb.z, acc[2][2]);
            acc[2][3] = fmaf(a.z, bb.w, acc[2][3]);
            acc[3][0] = fmaf(a.w, bb.x, acc[3][0]);
            acc[3][1] = fmaf(a.w, bb.y, acc[3][1]);
            acc[3][2] = fmaf(a.w, bb.z, acc[3][2]);
            acc[3][3] = fmaf(a.w, bb.w, acc[3][3]);
        }
        __syncthreads();
    }
#pragma unroll
    for (int ii = 0; ii < 4; ++ii) {
        float4 v = {acc[ii][0], acc[ii][1], acc[ii][2], acc[ii][3]};
        *reinterpret_cast<float4*>(
            &C[(size_t)b * sC + (size_t)(m0 + ty * 4 + ii) * FF + n0 + tx * 4]) = v;
    }
}

// ---------------------------------------------------------------------------
// Launch
// ---------------------------------------------------------------------------
extern "C" void kernel_launch(void* const* d_in, const int* in_sizes, int n_in,
                              void* d_out, int out_size, void* d_ws, size_t ws_size,
                              hipStream_t stream) {
    const float* x_ori = (const float*)d_in[0];
    const float* x     = (const float*)d_in[1];
    const float* c     = (const float*)d_in[2];
    const int*   adj   = (const int*)d_in[3];
    const float* Wfc   = (const float*)d_in[4];
    const float* Wdc   = (const float*)d_in[5];
    const float* Wqv   = (const float*)d_in[6];
    const float* Wkv   = (const float*)d_in[7];
    const float* Wqc   = (const float*)d_in[8];
    const float* Wkc   = (const float*)d_in[9];
    const float* Wa    = (const float*)d_in[10];
    const float* Wu    = (const float*)d_in[11];
    float* out = (float*)d_out;

    float* ws   = (float*)d_ws;
    float* tb   = ws + OFF_T;
    float* mb   = ws + OFF_M;
    float* mq   = ws + OFF_MQ;
    float* mk   = ws + OFF_MK;
    float* WqE  = ws + OFF_WQE;
    float* WkE  = ws + OFF_WKE;
    float* sq   = ws + OFF_SQ;
    float* sk   = ws + OFF_SK;
    float* attn = ws + OFF_ATTN;
    float* newx = ws + OFF_NEWX;

    dim3 blk(256);

    // m-chain: t = elu(c@Wfc); m = t@Wdc; mq = m@Wqc; mk = m@Wkc
    k_matvec<<<dim3(2, BSZ), blk, 0, stream>>>(c, Wfc, tb, 1);
    k_matvec<<<dim3(2, BSZ), blk, 0, stream>>>(tb, Wdc, mb, 0);
    k_mqk<<<dim3(2, BSZ), blk, 0, stream>>>(mb, Wqc, Wkc, mq, mk);

    // effective low-rank weights
    k_weff<<<dim3(16, BSZ), blk, 0, stream>>>(Wqv, Wa, mq, WqE, 0);
    k_weff<<<dim3(16, BSZ), blk, 0, stream>>>(Wkv, Wa, mk, WkE, FF);

    // sq / sk
    k_sqsk<<<dim3(32, BSZ), blk, 0, stream>>>(x, x_ori, WqE, WkE, sq, sk);

    // scores + mask + softmax -> attn
    k_attn<<<dim3(NN, BSZ), blk, 0, stream>>>(adj, sq, sk, attn);

    // new_x = attn @ x
    k_gemm64<<<dim3(8, 8, BSZ), blk, 0, stream>>>(
        attn, (size_t)NN * NN, attn, (size_t)NN * NN,
        x, (size_t)NN * FF, newx, (size_t)NN * FF, 512);

    // out = [x | new_x] @ Wu
    k_gemm64<<<dim3(8, 8, BSZ), blk, 0, stream>>>(
        x, (size_t)NN * FF, newx, (size_t)NN * FF,
        Wu, (size_t)0, out, (size_t)NN * FF, 1024);
}

// Round 2
// 379.094 us; speedup vs baseline: 1.7616x; 1.7616x over previous
//
#include <hip/hip_runtime.h>
#include <hip/hip_bf16.h>
#include <cstddef>
#include <cstdint>

static constexpr int BSZ  = 8;
static constexpr int NN   = 512;
static constexpr int FF   = 512;
static constexpr int RR   = 16;
static constexpr int TWOF = 1024;

typedef __attribute__((ext_vector_type(8))) short short8;   // 8 bf16 in 4 VGPRs
typedef __attribute__((ext_vector_type(4))) float f32x4;

__device__ __forceinline__ ushort bf16_bits(float v) {
    union { __hip_bfloat16 h; ushort u; } cvt;
    cvt.h = __float2bfloat16(v);
    return cvt.u;
}

// ---------------------------------------------------------------------------
// Workspace layout (byte offsets, 256B aligned)
// ---------------------------------------------------------------------------
static constexpr size_t OFF_TB     = 0;         // f32 [8][512]
static constexpr size_t OFF_MB     = 16384;     // f32 [8][512]
static constexpr size_t OFF_MQ     = 32768;     // f32 [8][512]
static constexpr size_t OFF_MK     = 49152;     // f32 [8][512]
static constexpr size_t OFF_SQ     = 65536;     // f32 [8][512][16]
static constexpr size_t OFF_SK     = 327680;    // f32 [8][512][16]
static constexpr size_t OFF_WQET   = 589824;    // bf16 [8][16][1024]
static constexpr size_t OFF_WKET   = 851968;    // bf16 [8][16][1024]
static constexpr size_t OFF_ATTN   = 1114112;   // bf16 [8][512][512]
static constexpr size_t OFF_XBF    = 5308416;   // bf16 [8][512][512]
static constexpr size_t OFF_XTBF   = 9502720;   // bf16 [8][512][512]  (x^T per b)
static constexpr size_t OFF_XORIBF = 13697024;  // bf16 [8][512][512]
static constexpr size_t OFF_NEWXBF = 17891328;  // bf16 [8][512][512]
static constexpr size_t OFF_WUT    = 22085632;  // bf16 [512][1024]    (Wu^T)

// ---------------------------------------------------------------------------
// cvt: fp32 -> bf16, 8 elems/thread. grid: n/2048 blocks of 256
// ---------------------------------------------------------------------------
__global__ __launch_bounds__(256) void k_cvt(const float* __restrict__ in,
                                             ushort* __restrict__ out) {
    int idx = blockIdx.x * 256 + threadIdx.x;
    float4 a = ((const float4*)in)[idx * 2];
    float4 b = ((const float4*)in)[idx * 2 + 1];
    uint4 s;
    s.x = (uint)bf16_bits(a.x) | ((uint)bf16_bits(a.y) << 16);
    s.y = (uint)bf16_bits(a.z) | ((uint)bf16_bits(a.w) << 16);
    s.z = (uint)bf16_bits(b.x) | ((uint)bf16_bits(b.y) << 16);
    s.w = (uint)bf16_bits(b.z) | ((uint)bf16_bits(b.w) << 16);
    ((uint4*)out)[idx] = s;
}

// ---------------------------------------------------------------------------
// x -> x_bf (same layout) + xT_bf (transposed per batch). 32x32 tiles.
// grid (F/32, N/32, 8), block (32,8)
// ---------------------------------------------------------------------------
__global__ __launch_bounds__(256) void k_xt(const float* __restrict__ x,
                                            ushort* __restrict__ x_bf,
                                            ushort* __restrict__ xT_bf) {
    __shared__ float tile[32][33];
    int b = blockIdx.z;
    int i0 = blockIdx.y * 32, f0 = blockIdx.x * 32;
    int c = threadIdx.x, r0 = threadIdx.y;
#pragma unroll
    for (int rr = 0; rr < 32; rr += 8) {
        int i = i0 + r0 + rr;
        float v = x[((size_t)b * NN + i) * FF + f0 + c];
        tile[r0 + rr][c] = v;
        x_bf[((size_t)b * NN + i) * FF + f0 + c] = bf16_bits(v);
    }
    __syncthreads();
#pragma unroll
    for (int rr = 0; rr < 32; rr += 8) {
        int f = f0 + r0 + rr;
        xT_bf[((size_t)b * FF + f) * NN + i0 + c] = bf16_bits(tile[c][r0 + rr]);
    }
}

// ---------------------------------------------------------------------------
// Wu [1024][512] -> WuT_bf [512][1024]. grid (32 f-tiles, 16 o-tiles), block (32,8)
// ---------------------------------------------------------------------------
__global__ __launch_bounds__(256) void k_wuT(const float* __restrict__ Wu,
                                             ushort* __restrict__ WuT) {
    __shared__ float tile[32][33];
    int f0 = blockIdx.x * 32, o0 = blockIdx.y * 32;
    int c = threadIdx.x, r0 = threadIdx.y;
#pragma unroll
    for (int rr = 0; rr < 32; rr += 8) {
        tile[r0 + rr][c] = Wu[(size_t)(f0 + r0 + rr) * FF + o0 + c];
    }
    __syncthreads();
#pragma unroll
    for (int rr = 0; rr < 32; rr += 8) {
        WuT[(size_t)(o0 + r0 + rr) * TWOF + f0 + c] = bf16_bits(tile[c][r0 + rr]);
    }
}

// ---------------------------------------------------------------------------
// Batched matvec with 4-way k-split: vout[b,f] = act(vin[b,:] @ W[:,f])
// grid (8 fb, 8 b), block 256 = (64 f, 4 kq)
// ---------------------------------------------------------------------------
__global__ __launch_bounds__(256) void k_matvec(const float* __restrict__ vin,
                                                const float* __restrict__ W,
                                                float* __restrict__ vout,
                                                int elu_out) {
    __shared__ float red[4][64];
    int b = blockIdx.y;
    int f0 = blockIdx.x * 64;
    int t = threadIdx.x;
    int f = t & 63, kq = t >> 6;
    const float* vb = vin + (size_t)b * FF;
    float acc = 0.f;
    int ks = kq * 128;
#pragma unroll 4
    for (int k = ks; k < ks + 128; ++k)
        acc = fmaf(vb[k], W[(size_t)k * FF + f0 + f], acc);
    red[kq][f] = acc;
    __syncthreads();
    if (kq == 0) {
        acc += red[1][f] + red[2][f] + red[3][f];
        if (elu_out) acc = (acc > 0.f) ? acc : expm1f(acc);
        vout[(size_t)b * FF + f0 + f] = acc;
    }
}

// mq = m @ Wqc ; mk = m @ Wkc (same structure, two accumulators)
__global__ __launch_bounds__(256) void k_mqk(const float* __restrict__ m,
                                             const float* __restrict__ Wqc,
                                             const float* __restrict__ Wkc,
                                             float* __restrict__ mq,
                                             float* __restrict__ mk) {
    __shared__ float redq[4][64];
    __shared__ float redk[4][64];
    int b = blockIdx.y;
    int f0 = blockIdx.x * 64;
    int t = threadIdx.x;
    int f = t & 63, kq = t >> 6;
    const float* mb = m + (size_t)b * FF;
    float aq = 0.f, ak = 0.f;
    int ks = kq * 128;
#pragma unroll 4
    for (int k = ks; k < ks + 128; ++k) {
        float mv = mb[k];
        aq = fmaf(mv, Wqc[(size_t)k * FF + f0 + f], aq);
        ak = fmaf(mv, Wkc[(size_t)k * FF + f0 + f], ak);
    }
    redq[kq][f] = aq;
    redk[kq][f] = ak;
    __syncthreads();
    if (kq == 0) {
        aq += redq[1][f] + redq[2][f] + redq[3][f];
        ak += redk[1][f] + redk[2][f] + redk[3][f];
        mq[(size_t)b * FF + f0 + f] = aq;
        mk[(size_t)b * FF + f0 + f] = ak;
    }
}

// ---------------------------------------------------------------------------
// W_eff^T[b,r,k] = sum_f W[k,f] * mvec[b,f] * Wa[waRowOff+f, r]  (bf16 out)
// grid (16 kchunks, 8 b), block 256
// ---------------------------------------------------------------------------
__global__ __launch_bounds__(256) void k_weff(const float* __restrict__ W,
                                              const float* __restrict__ Wa,
                                              const float* __restrict__ mvec,
                                              ushort* __restrict__ WeffT,
                                              int waRowOff) {
    __shared__ float4 wa4[FF * 4];  // [f][r4] scaled Wa, 32 KiB
    int tid = threadIdx.x;
    int b = blockIdx.y;
    const float* mv = mvec + (size_t)b * FF;
#pragma unroll
    for (int q = 0; q < 8; ++q) {
        int idx = tid + q * 256;
        int f = idx >> 2, rq = idx & 3;
        float4 w = *reinterpret_cast<const float4*>(Wa + (size_t)(waRowOff + f) * RR + rq * 4);
        float s = mv[f];
        float4 o;
        o.x = w.x * s; o.y = w.y * s; o.z = w.z * s; o.w = w.w * s;
        wa4[idx] = o;
    }
    __syncthreads();
    int k_l = tid >> 2, r4 = tid & 3;
    int k = blockIdx.x * 64 + k_l;
    const float* Wrow = W + (size_t)k * FF;
    float4 acc = {0.f, 0.f, 0.f, 0.f};
#pragma unroll 4
    for (int f = 0; f < FF; ++f) {
        float w = Wrow[f];
        float4 v = wa4[f * 4 + r4];
        acc.x = fmaf(w, v.x, acc.x);
        acc.y = fmaf(w, v.y, acc.y);
        acc.z = fmaf(w, v.z, acc.z);
        acc.w = fmaf(w, v.w, acc.w);
    }
    // transposed bf16 store: WeffT[b][r][k], r = r4*4..+3
    WeffT[((size_t)b * RR + r4 * 4 + 0) * TWOF + k] = bf16_bits(acc.x);
    WeffT[((size_t)b * RR + r4 * 4 + 1) * TWOF + k] = bf16_bits(acc.y);
    WeffT[((size_t)b * RR + r4 * 4 + 2) * TWOF + k] = bf16_bits(acc.z);
    WeffT[((size_t)b * RR + r4 * 4 + 3) * TWOF + k] = bf16_bits(acc.w);
}

// ---------------------------------------------------------------------------
// sq/sk via MFMA: sq[b,i,r] = nodes[b,i,:] @ WqE[b,:,r]
// nodes k<512 from x_bf, k>=512 from xori_bf; B = WqEt/WkEt [b][16][1024]
// grid (8 m-tiles, 8 b), block 256 (4 waves x 16 rows)
// ---------------------------------------------------------------------------
__global__ __launch_bounds__(256) void k_sqsk_mfma(const ushort* __restrict__ x_bf,
                                                   const ushort* __restrict__ xori_bf,
                                                   const ushort* __restrict__ WqEt,
                                                   const ushort* __restrict__ WkEt,
                                                   float* __restrict__ sq,
                                                   float* __restrict__ sk) {
    __shared__ ushort As[64 * 72];
    __shared__ ushort Bq[16 * 72];
    __shared__ ushort Bk[16 * 72];
    int t = threadIdx.x;
    int m0 = blockIdx.x * 64;
    int b = blockIdx.y;
    int row = t >> 2, c4 = t & 3;
    int lane = t & 63, w = t >> 6;
    int m_l = lane & 15, q = lane >> 4;
    f32x4 aq = {0.f, 0.f, 0.f, 0.f}, ak = {0.f, 0.f, 0.f, 0.f};
    for (int k0 = 0; k0 < TWOF; k0 += 32) {
        const ushort* src; int kc;
        if (k0 < FF) { src = x_bf;    kc = k0; }
        else         { src = xori_bf; kc = k0 - FF; }
        uint4 av = *(const uint4*)(src + ((size_t)b * NN + m0 + row) * FF + kc + c4 * 8);
        *(uint4*)(&As[row * 72 + c4 * 8]) = av;
        if (t < 64) {
            uint4 bv = *(const uint4*)(WqEt + ((size_t)b * RR + row) * TWOF + k0 + c4 * 8);
            *(uint4*)(&Bq[row * 72 + c4 * 8]) = bv;
        } else if (t < 128) {
            int rr = row - 16;
            uint4 bv = *(const uint4*)(WkEt + ((size_t)b * RR + rr) * TWOF + k0 + c4 * 8);
            *(uint4*)(&Bk[rr * 72 + c4 * 8]) = bv;
        }
        __syncthreads();
        short8 af  = *(const short8*)(&As[(w * 16 + m_l) * 72 + q * 8]);
        short8 bqf = *(const short8*)(&Bq[m_l * 72 + q * 8]);
        short8 bkf = *(const short8*)(&Bk[m_l * 72 + q * 8]);
        aq = __builtin_amdgcn_mfma_f32_16x16x32_bf16(af, bqf, aq, 0, 0, 0);
        ak = __builtin_amdgcn_mfma_f32_16x16x32_bf16(af, bkf, ak, 0, 0, 0);
        __syncthreads();
    }
#pragma unroll
    for (int r = 0; r < 4; ++r) {
        int i = m0 + w * 16 + q * 4 + r;
        sq[((size_t)b * NN + i) * RR + m_l] = aq[r];
        sk[((size_t)b * NN + i) * RR + m_l] = ak[r];
    }
}

// ---------------------------------------------------------------------------
// Fused scores + mask + softmax -> attn_bf.  grid (512 i, 8 b), block 256.
// ---------------------------------------------------------------------------
__global__ __launch_bounds__(256) void k_attn(const int* __restrict__ adj,
                                              const float* __restrict__ sq,
                                              const float* __restrict__ sk,
                                              ushort* __restrict__ attn_bf) {
    int t = threadIdx.x;
    int i = blockIdx.x;
    int b = blockIdx.y;
    __shared__ float sqv_s[RR];
    __shared__ float redmax[4];
    __shared__ float redsum[4];
    __shared__ float bc_max;
    __shared__ float bc_sum;
    if (t < RR) sqv_s[t] = sq[((size_t)b * NN + i) * RR + t];
    __syncthreads();
    float sv[RR];
#pragma unroll
    for (int r = 0; r < RR; ++r) sv[r] = sqv_s[r];

    float z[2];
#pragma unroll
    for (int jj = 0; jj < 2; ++jj) {
        int j = t + jj * 256;
        size_t base = ((size_t)(b * NN + i) * NN + j) * RR;
        const int4* ap = reinterpret_cast<const int4*>(adj + base);
        int4 a0 = ap[0], a1 = ap[1], a2 = ap[2], a3 = ap[3];
        const float4* kp = reinterpret_cast<const float4*>(sk + ((size_t)b * NN + j) * RR);
        float4 s0 = kp[0], s1 = kp[1], s2 = kp[2], s3 = kp[3];
        int sum_adj = a0.x + a0.y + a0.z + a0.w + a1.x + a1.y + a1.z + a1.w +
                      a2.x + a2.y + a2.z + a2.w + a3.x + a3.y + a3.z + a3.w;
        float ssum = 0.f;
#define LR_TERM(SVAL, AVAL, RIDX)                                   \
        { float v_ = sv[RIDX] + (SVAL);                             \
          v_ = fmaxf(v_, 0.2f * v_);                                \
          ssum = fmaf(v_, (float)(AVAL), ssum); }
        LR_TERM(s0.x, a0.x, 0)  LR_TERM(s0.y, a0.y, 1)
        LR_TERM(s0.z, a0.z, 2)  LR_TERM(s0.w, a0.w, 3)
        LR_TERM(s1.x, a1.x, 4)  LR_TERM(s1.y, a1.y, 5)
        LR_TERM(s1.z, a1.z, 6)  LR_TERM(s1.w, a1.w, 7)
        LR_TERM(s2.x, a2.x, 8)  LR_TERM(s2.y, a2.y, 9)
        LR_TERM(s2.z, a2.z, 10) LR_TERM(s2.w, a2.w, 11)
        LR_TERM(s3.x, a3.x, 12) LR_TERM(s3.y, a3.y, 13)
        LR_TERM(s3.z, a3.z, 14) LR_TERM(s3.w, a3.w, 15)
#undef LR_TERM
        z[jj] = (sum_adj > 0) ? ssum : -9e15f;
    }

    int wv = t >> 6, ln = t & 63;
    float lm = fmaxf(z[0], z[1]);
    for (int off = 32; off; off >>= 1) lm = fmaxf(lm, __shfl_xor(lm, off, 64));
    if (ln == 0) redmax[wv] = lm;
    __syncthreads();
    if (t == 0) bc_max = fmaxf(fmaxf(redmax[0], redmax[1]), fmaxf(redmax[2], redmax[3]));
    __syncthreads();
    float mx = bc_max;
    float e0 = __expf(z[0] - mx);
    float e1 = __expf(z[1] - mx);
    float ls = e0 + e1;
    for (int off = 32; off; off >>= 1) ls += __shfl_xor(ls, off, 64);
    if (ln == 0) redsum[wv] = ls;
    __syncthreads();
    if (t == 0) bc_sum = redsum[0] + redsum[1] + redsum[2] + redsum[3];
    __syncthreads();
    float inv = 1.f / bc_sum;
    ushort* outp = attn_bf + (size_t)(b * NN + i) * NN;
    outp[t] = bf16_bits(e0 * inv);
    outp[t + 256] = bf16_bits(e1 * inv);
}

// ---------------------------------------------------------------------------
// bf16 MFMA GEMM: C[b] (MxN) = A[b] (MxK, row-major, split at k=512) @ BT^T
// BT is [N][K] row-major (B transposed), bf16. 64x64 tile, BK=32.
// block 256 = 4 waves, wave w computes rows w*16..+16 x all 64 cols.
// grid (N/64, M/64, 8)
// ---------------------------------------------------------------------------
__global__ __launch_bounds__(256) void k_gemm_mfma(const ushort* __restrict__ A1, size_t sA1,
                                                   const ushort* __restrict__ A2, size_t sA2,
                                                   const ushort* __restrict__ BT, size_t sBT,
                                                   float* __restrict__ Cf,
                                                   ushort* __restrict__ Cb, size_t sC,
                                                   int K, int ldBT) {
    __shared__ ushort As[64 * 72];
    __shared__ ushort Bs[64 * 72];
    int t = threadIdx.x;
    int n0 = blockIdx.x * 64, m0 = blockIdx.y * 64, b = blockIdx.z;
    int row = t >> 2, c4 = t & 3;
    int lane = t & 63, w = t >> 6;
    int m_l = lane & 15, q = lane >> 4;
    f32x4 acc[4] = {{0.f,0.f,0.f,0.f},{0.f,0.f,0.f,0.f},{0.f,0.f,0.f,0.f},{0.f,0.f,0.f,0.f}};
    const ushort* BTb = BT + (size_t)b * sBT;
    for (int k0 = 0; k0 < K; k0 += 32) {
        const ushort* Aab; int kc;
        if (k0 < FF) { Aab = A1 + (size_t)b * sA1; kc = k0; }
        else         { Aab = A2 + (size_t)b * sA2; kc = k0 - FF; }
        uint4 av = *(const uint4*)(Aab + (size_t)(m0 + row) * FF + kc + c4 * 8);
        uint4 bv = *(const uint4*)(BTb + (size_t)(n0 + row) * ldBT + k0 + c4 * 8);
        *(uint4*)(&As[row * 72 + c4 * 8]) = av;
        *(uint4*)(&Bs[row * 72 + c4 * 8]) = bv;
        __syncthreads();
        short8 af = *(const short8*)(&As[(w * 16 + m_l) * 72 + q * 8]);
#pragma unroll
        for (int nb = 0; nb < 4; ++nb) {
            short8 bfr = *(const short8*)(&Bs[(nb * 16 + m_l) * 72 + q * 8]);
            acc[nb] = __builtin_amdgcn_mfma_f32_16x16x32_bf16(af, bfr, acc[nb], 0, 0, 0);
        }
        __syncthreads();
    }
#pragma unroll
    for (int nb = 0; nb < 4; ++nb) {
#pragma unroll
        for (int r = 0; r < 4; ++r) {
            int mi = m0 + w * 16 + q * 4 + r;
            int ni = n0 + nb * 16 + m_l;
            float v = acc[nb][r];
            if (Cb) Cb[(size_t)b * sC + (size_t)mi * FF + ni] = bf16_bits(v);
            else    Cf[(size_t)b * sC + (size_t)mi * FF + ni] = v;
        }
    }
}

// ---------------------------------------------------------------------------
// Launch
// ---------------------------------------------------------------------------
extern "C" void kernel_launch(void* const* d_in, const int* in_sizes, int n_in,
                              void* d_out, int out_size, void* d_ws, size_t ws_size,
                              hipStream_t stream) {
    const float* x_ori = (const float*)d_in[0];
    const float* x     = (const float*)d_in[1];
    const float* c     = (const float*)d_in[2];
    const int*   adj   = (const int*)d_in[3];
    const float* Wfc   = (const float*)d_in[4];
    const float* Wdc   = (const float*)d_in[5];
    const float* Wqv   = (const float*)d_in[6];
    const float* Wkv   = (const float*)d_in[7];
    const float* Wqc   = (const float*)d_in[8];
    const float* Wkc   = (const float*)d_in[9];
    const float* Wa    = (const float*)d_in[10];
    const float* Wu    = (const float*)d_in[11];
    float* out = (float*)d_out;

    char* ws = (char*)d_ws;
    float*  tb      = (float*)(ws + OFF_TB);
    float*  mb      = (float*)(ws + OFF_MB);
    float*  mq      = (float*)(ws + OFF_MQ);
    float*  mk      = (float*)(ws + OFF_MK);
    float*  sq      = (float*)(ws + OFF_SQ);
    float*  sk      = (float*)(ws + OFF_SK);
    ushort* WqEt    = (ushort*)(ws + OFF_WQET);
    ushort* WkEt    = (ushort*)(ws + OFF_WKET);
    ushort* attn_bf = (ushort*)(ws + OFF_ATTN);
    ushort* x_bf    = (ushort*)(ws + OFF_XBF);
    ushort* xT_bf   = (ushort*)(ws + OFF_XTBF);
    ushort* xori_bf = (ushort*)(ws + OFF_XORIBF);
    ushort* newx_bf = (ushort*)(ws + OFF_NEWXBF);
    ushort* WuT     = (ushort*)(ws + OFF_WUT);

    dim3 blk(256);

    // bf16 conversions / transposes
    k_cvt<<<dim3(1024), blk, 0, stream>>>(x_ori, xori_bf);
    k_xt<<<dim3(16, 16, BSZ), dim3(32, 8), 0, stream>>>(x, x_bf, xT_bf);
    k_wuT<<<dim3(32, 16), dim3(32, 8), 0, stream>>>(Wu, WuT);

    // m-chain
    k_matvec<<<dim3(8, BSZ), blk, 0, stream>>>(c, Wfc, tb, 1);
    k_matvec<<<dim3(8, BSZ), blk, 0, stream>>>(tb, Wdc, mb, 0);
    k_mqk<<<dim3(8, BSZ), blk, 0, stream>>>(mb, Wqc, Wkc, mq, mk);

    // effective low-rank weights (transposed bf16)
    k_weff<<<dim3(16, BSZ), blk, 0, stream>>>(Wqv, Wa, mq, WqEt, 0);
    k_weff<<<dim3(16, BSZ), blk, 0, stream>>>(Wkv, Wa, mk, WkEt, FF);

    // sq / sk via MFMA
    k_sqsk_mfma<<<dim3(8, BSZ), blk, 0, stream>>>(x_bf, xori_bf, WqEt, WkEt, sq, sk);

    // scores + mask + softmax -> attn (bf16)
    k_attn<<<dim3(NN, BSZ), blk, 0, stream>>>(adj, sq, sk, attn_bf);

    // new_x = attn @ x   (A=attn_bf, BT=xT_bf, out bf16)
    k_gemm_mfma<<<dim3(8, 8, BSZ), blk, 0, stream>>>(
        attn_bf, (size_t)NN * NN, attn_bf, (size_t)NN * NN,
        xT_bf, (size_t)FF * NN, nullptr, newx_bf, (size_t)NN * FF, FF, NN);

    // out = [x | new_x] @ Wu   (A1=x_bf, A2=newx_bf, BT=WuT shared, out fp32)
    k_gemm_mfma<<<dim3(8, 8, BSZ), blk, 0, stream>>>(
        x_bf, (size_t)NN * FF, newx_bf, (size_t)NN * FF,
        WuT, (size_t)0, out, nullptr, (size_t)NN * FF, TWOF, TWOF);
}